// Round 6
// baseline (113.711 us; speedup 1.0000x reference)
//
#include <hip/hip_runtime.h>
#include <math.h>

#define H 2048
#define W 2048
#define SEG 256
#define L 8             // rows per segment
#define BIG (1 << 20)
#define DCLAMP 2900     // > max possible distance; f <= 8.41e6, exact in fp32
#define TILE 256        // columns per k4 block
#define HALO 128        // halo columns each side (window >HALO falls back to global)
#define LW (TILE + 2 * HALO)  // 512

// ---------------------------------------------------------------------------
// K1: per (column-group, segment): 8-row local down-scan, 4 columns/thread via
// float4. Byte-encodes: v in 0..7 = exact down-dist (0 <=> background);
// v = 128+m = BIG-encoded (m = rows since segment top + 1).
// Summaries: A[s][j] = bottom-row down value, B[s][j] = top-row up value.
// Thread (0,0,0) zero-inits maxp (stream-ordered before K4's atomics).
// ---------------------------------------------------------------------------
__global__ void k1_down(const float* __restrict__ img, unsigned char* __restrict__ down,
                        int* __restrict__ A, int* __restrict__ B,
                        unsigned int* __restrict__ maxp) {
    const int tid = threadIdx.x;
    const int bx = blockIdx.x;          // 0..1
    const int s  = blockIdx.y;          // 0..255
    const int j0 = bx * 1024 + tid * 4;
    const int r0 = s * L;
    if (bx == 0 && s == 0 && tid == 0) *maxp = 0u;

    int d[4]  = {BIG, BIG, BIG, BIG};
    int fb[4] = {-1, -1, -1, -1};
#pragma unroll
    for (int i = 0; i < L; ++i) {
        const float4 v = *(const float4*)(img + (size_t)(r0 + i) * W + j0);
        float vv[4] = {v.x, v.y, v.z, v.w};
        unsigned enc4 = 0;
#pragma unroll
        for (int k = 0; k < 4; ++k) {
            bool z = vv[k] <= 0.5f;                 // background
            d[k] = z ? 0 : d[k] + 1;
            fb[k] = (z && fb[k] < 0) ? i : fb[k];
            unsigned e = (d[k] < BIG) ? (unsigned)d[k] : (unsigned)(128 + (d[k] - BIG));
            enc4 |= e << (8 * k);
        }
        *(unsigned*)(down + (size_t)(r0 + i) * W + j0) = enc4;
    }
    *(int4*)(A + (size_t)s * W + j0) = make_int4(d[0], d[1], d[2], d[3]);
    *(int4*)(B + (size_t)s * W + j0) =
        make_int4(fb[0] >= 0 ? fb[0] : BIG + L, fb[1] >= 0 ? fb[1] : BIG + L,
                  fb[2] >= 0 ? fb[2] : BIG + L, fb[3] >= 0 ? fb[3] : BIG + L);
}

// ---------------------------------------------------------------------------
// K2: resolve carries across 256 segments; 4096 threads (one per column+dir).
// unroll 16: loads are address-independent, so each batch pipelines.
// CD[s][j] = down-dist at row just above segment s; CU[s][j] = up-dist at
// row just below segment s (BIG-encoded if none).
// ---------------------------------------------------------------------------
__global__ void k2_carry(const int* __restrict__ A, const int* __restrict__ B,
                         int* __restrict__ CD, int* __restrict__ CU) {
    int gt = blockIdx.x * blockDim.x + threadIdx.x;   // 0..4095
    int col = gt & (W - 1);
    if (gt < W) {
        int c = BIG;
#pragma unroll 16
        for (int s = 0; s < SEG; ++s) {
            int a = A[(size_t)s * W + col];
            CD[(size_t)s * W + col] = c;
            c = (a < BIG) ? a : a - BIG + c;
        }
    } else {
        int c = BIG;
#pragma unroll 16
        for (int s = SEG - 1; s >= 0; --s) {
            int b = B[(size_t)s * W + col];
            CU[(size_t)s * W + col] = c;
            c = (b < BIG) ? b : b - BIG + c;
        }
    }
}

// ---------------------------------------------------------------------------
// exact f at (row r0+i, col) decoded from global down bytes + carries.
// Only used by the (never-taken for this input) beyond-halo fallback.
// ---------------------------------------------------------------------------
__device__ float f_at(const unsigned char* __restrict__ down,
                      const int* __restrict__ CD, const int* __restrict__ CU,
                      int s, int i, int col) {
    int r0 = s * L;
    int u = CU[(size_t)s * W + col];
    for (int t = L - 1; t > i; --t)
        u = down[(size_t)(r0 + t) * W + col] ? u + 1 : 0;
    unsigned v = down[(size_t)(r0 + i) * W + col];
    u = v ? u + 1 : 0;
    int dv = (v < 128u) ? (int)v : (int)(v - 128u) + CD[(size_t)s * W + col];
    int dd = min(min(dv, u), DCLAMP);
    return (float)dd * (float)dd;
}

// ---------------------------------------------------------------------------
// K4: one block per (256-col tile, 8-row segment) = 2048 blocks (8/CU).
// Decodes down bytes + carries for tile+halo straight into a 16 KB LDS f-tile
// (f never touches HBM), then per-column early-exit row scan:
//   D[i,j] = min_d f[i,j±d] + d^2; stop when d*d >= best (exact).
// If the window would exceed HALO (best > (HALO+1)^2), falls back to exact
// global decode — preserves correctness for any input. Writes sqrt(D) fp32,
// one atomicMax per block.
// ---------------------------------------------------------------------------
__global__ void __launch_bounds__(256)
k4_row(const unsigned char* __restrict__ down, const int* __restrict__ CD,
       const int* __restrict__ CU, float* __restrict__ dist,
       unsigned int* __restrict__ maxp) {
    __shared__ float ftile[L][LW];   // 16 KB
    __shared__ float smax[4];
    const int tid = threadIdx.x;
    const int s  = blockIdx.y;
    const int r0 = s * L;
    const int c0 = blockIdx.x * TILE;

    // ---- decode 2 columns/thread into LDS (cols c0-HALO .. c0+TILE+HALO)
    {
        int lc = tid * 2;
        int gc = c0 - HALO + lc;       // even
        if (gc >= 0 && gc < W) {       // gc+1 < W holds (W even)
            int2 dcv = *(const int2*)(CD + (size_t)s * W + gc);
            int2 ucv = *(const int2*)(CU + (size_t)s * W + gc);
            int dc0 = dcv.x, dc1 = dcv.y;
            int u0 = ucv.x, u1 = ucv.y;
#pragma unroll
            for (int i = L - 1; i >= 0; --i) {
                unsigned v2 = *(const unsigned short*)(down + (size_t)(r0 + i) * W + gc);
                unsigned v0 = v2 & 0xffu, v1 = v2 >> 8;
                u0 = v0 ? u0 + 1 : 0;
                u1 = v1 ? u1 + 1 : 0;
                int dv0 = (v0 < 128u) ? (int)v0 : (int)(v0 - 128u) + dc0;
                int dv1 = (v1 < 128u) ? (int)v1 : (int)(v1 - 128u) + dc1;
                int dd0 = min(min(dv0, u0), DCLAMP);
                int dd1 = min(min(dv1, u1), DCLAMP);
                float f0 = (float)dd0 * (float)dd0;
                float f1 = (float)dd1 * (float)dd1;
                *(float2*)&ftile[i][lc] = make_float2(f0, f1);
            }
        } else {
#pragma unroll
            for (int i = 0; i < L; ++i)
                *(float2*)&ftile[i][lc] = make_float2(1e9f, 1e9f);  // pad: never wins
        }
    }
    __syncthreads();

    // ---- early-exit scan: 1 column/thread over 8 rows
    const int jj = c0 + tid;     // global col
    const int lj = HALO + tid;   // LDS col; lj-d >= 0 and lj+d <= 511 for d <= HALO
    float res[L];
    float lmax = 0.0f;
    for (int i = 0; i < L; ++i) {
        float best = ftile[i][lj];
        for (int d = 1; d <= HALO && (float)(d * d) < best; ++d) {
            float q = (float)(d * d);
            best = fminf(best, ftile[i][lj - d] + q);
            best = fminf(best, ftile[i][lj + d] + q);
        }
        if ((float)((HALO + 1) * (HALO + 1)) < best) {
            // exact beyond-halo fallback (never taken for random 50% mask)
            for (int d = HALO + 1; d < W && (float)(d * d) < best; ++d) {
                float q = (float)(d * d);
                int jm = jj - d, jp = jj + d;
                if (jm >= 0) best = fminf(best, f_at(down, CD, CU, s, i, jm) + q);
                if (jp < W)  best = fminf(best, f_at(down, CD, CU, s, i, jp) + q);
            }
        }
        float r = sqrtf(best);
        res[i] = r;
        lmax = fmaxf(lmax, r);
    }
#pragma unroll
    for (int i = 0; i < L; ++i)
        dist[(size_t)(r0 + i) * W + jj] = res[i];

    for (int o = 32; o > 0; o >>= 1) lmax = fmaxf(lmax, __shfl_down(lmax, o, 64));
    if ((tid & 63) == 0) smax[tid >> 6] = lmax;
    __syncthreads();
    if (tid == 0)
        atomicMax(maxp, __float_as_uint(fmaxf(fmaxf(smax[0], smax[1]),
                                              fmaxf(smax[2], smax[3]))));
}

// ---------------------------------------------------------------------------
// K5: in-place normalize, float4 -> int4 (uint8 semantics: trunc(d/m*255)).
// ---------------------------------------------------------------------------
__global__ void k5_norm(int* __restrict__ out, const unsigned int* __restrict__ maxp) {
    size_t idx = ((size_t)blockIdx.x * blockDim.x + threadIdx.x) * 4;
    float m = __uint_as_float(*maxp);
    float4 dv = *(const float4*)((const float*)out + idx);
    float r[4] = {dv.x, dv.y, dv.z, dv.w};
    int o[4];
#pragma unroll
    for (int k = 0; k < 4; ++k) {
        float v = (m > 0.0f) ? (r[k] / m * 255.0f) : r[k];  // numpy op order
        v = fminf(fmaxf(v, 0.0f), 255.0f);
        o[k] = (int)v;                                      // trunc, like astype(uint8)
    }
    *(int4*)(out + idx) = make_int4(o[0], o[1], o[2], o[3]);
}

extern "C" void kernel_launch(void* const* d_in, const int* in_sizes, int n_in,
                              void* d_out, int out_size, void* d_ws, size_t ws_size,
                              hipStream_t stream) {
    const float* img = (const float*)d_in[0];
    int* out = (int*)d_out;

    // ws: down bytes (4 MB) | A | B | CD | CU (2 MB each) | maxp
    char* ws = (char*)d_ws;
    unsigned char* down = (unsigned char*)ws;
    int* A  = (int*)(ws + (size_t)H * W);
    int* B  = A + (size_t)SEG * W;
    int* CD = B + (size_t)SEG * W;
    int* CU = CD + (size_t)SEG * W;
    unsigned int* maxp = (unsigned int*)(CU + (size_t)SEG * W);

    dim3 blk(256);
    k1_down <<<dim3(2, SEG), blk, 0, stream>>>(img, down, A, B, maxp);
    k2_carry<<<dim3(2 * W / 256), blk, 0, stream>>>(A, B, CD, CU);
    k4_row  <<<dim3(W / TILE, SEG), blk, 0, stream>>>(down, CD, CU, (float*)out, maxp);
    k5_norm <<<dim3(H * W / 1024), blk, 0, stream>>>(out, maxp);
}

// Round 7
// 113.368 us; speedup vs baseline: 1.0030x; 1.0030x over previous
//
#include <hip/hip_runtime.h>
#include <math.h>

#define H 2048
#define W 2048
#define SEG 256
#define L 8             // rows per segment
#define NSS 16          // supersegments
#define SSL 16          // segments per supersegment
#define BIG (1 << 20)
#define DCLAMP 2900     // > max possible distance; f <= 8.41e6, exact in fp32
#define TILE 256        // columns per k4 block
#define HALO 128        // halo columns each side
#define LW (TILE + 2 * HALO)  // 512

// combine: carry c through a summary a (BIG-encoded = "no background inside")
__device__ __forceinline__ int dapply(int a, int c) { return (a < BIG) ? a : a - BIG + c; }

// ---------------------------------------------------------------------------
// K1: 8-row local down-scan, 4 columns/thread via float4. Byte-encode:
// 0..7 exact down-dist (0 <=> background); 128+m = BIG-encoded.
// A[s][j] = bottom-row down summary, B[s][j] = top-row up summary.
// ---------------------------------------------------------------------------
__global__ void k1_down(const float* __restrict__ img, unsigned char* __restrict__ down,
                        int* __restrict__ A, int* __restrict__ B,
                        unsigned int* __restrict__ maxp) {
    const int tid = threadIdx.x;
    const int bx = blockIdx.x;          // 0..1
    const int s  = blockIdx.y;          // 0..255
    const int j0 = bx * 1024 + tid * 4;
    const int r0 = s * L;
    if (bx == 0 && s == 0 && tid == 0) *maxp = 0u;

    int d[4]  = {BIG, BIG, BIG, BIG};
    int fb[4] = {-1, -1, -1, -1};
#pragma unroll
    for (int i = 0; i < L; ++i) {
        const float4 v = *(const float4*)(img + (size_t)(r0 + i) * W + j0);
        float vv[4] = {v.x, v.y, v.z, v.w};
        unsigned enc4 = 0;
#pragma unroll
        for (int k = 0; k < 4; ++k) {
            bool z = vv[k] <= 0.5f;
            d[k] = z ? 0 : d[k] + 1;
            fb[k] = (z && fb[k] < 0) ? i : fb[k];
            unsigned e = (d[k] < BIG) ? (unsigned)d[k] : (unsigned)(128 + (d[k] - BIG));
            enc4 |= e << (8 * k);
        }
        *(unsigned*)(down + (size_t)(r0 + i) * W + j0) = enc4;
    }
    *(int4*)(A + (size_t)s * W + j0) = make_int4(d[0], d[1], d[2], d[3]);
    *(int4*)(B + (size_t)s * W + j0) =
        make_int4(fb[0] >= 0 ? fb[0] : BIG + L, fb[1] >= 0 ? fb[1] : BIG + L,
                  fb[2] >= 0 ? fb[2] : BIG + L, fb[3] >= 0 ? fb[3] : BIG + L);
}

// ---------------------------------------------------------------------------
// K2a: supersegment summaries. 65536 threads: (dir, ss, col). 16 independent
// loads each, associative fold. SA/SB are 128 KB each.
// ---------------------------------------------------------------------------
__global__ void k2a_super(const int* __restrict__ A, const int* __restrict__ B,
                          int* __restrict__ SA, int* __restrict__ SB) {
    int gid = blockIdx.x * 256 + threadIdx.x;
    int dir = gid >> 15;
    int rem = gid & 32767;
    int ss  = rem >> 11;
    int col = rem & (W - 1);
    int base = ss * SSL;
    if (dir == 0) {
        int v = A[(size_t)base * W + col];
#pragma unroll
        for (int k = 1; k < SSL; ++k)
            v = dapply(A[(size_t)(base + k) * W + col], v);
        SA[ss * W + col] = v;
    } else {
        int v = B[(size_t)(base + SSL - 1) * W + col];
#pragma unroll
        for (int k = SSL - 2; k >= 0; --k)
            v = dapply(B[(size_t)(base + k) * W + col], v);
        SB[ss * W + col] = v;
    }
}

// ---------------------------------------------------------------------------
// K2b: scan the 16 supersegments per (col, dir). 4096 threads, 16 steps.
// CSD[ss][col] = down-carry at row just above superseg ss;
// CSU[ss][col] = up-carry at row just below superseg ss.
// ---------------------------------------------------------------------------
__global__ void k2b_scan(const int* __restrict__ SA, const int* __restrict__ SB,
                         int* __restrict__ CSD, int* __restrict__ CSU) {
    int gid = blockIdx.x * 256 + threadIdx.x;   // 0..4095
    int col = gid & (W - 1);
    if (gid < W) {
        int c = BIG;
#pragma unroll
        for (int ss = 0; ss < NSS; ++ss) {
            CSD[ss * W + col] = c;
            c = dapply(SA[ss * W + col], c);
        }
    } else {
        int c = BIG;
#pragma unroll
        for (int ss = NSS - 1; ss >= 0; --ss) {
            CSU[ss * W + col] = c;
            c = dapply(SB[ss * W + col], c);
        }
    }
}

// ---------------------------------------------------------------------------
// helper for the (never-taken) beyond-halo fallback: exact f from scratch.
// ---------------------------------------------------------------------------
__device__ float f_at(const unsigned char* __restrict__ down,
                      const int* __restrict__ A, const int* __restrict__ B,
                      const int* __restrict__ CSD, const int* __restrict__ CSU,
                      int s, int i, int col) {
    int ss = s >> 4, base = ss << 4;
    int dc = CSD[ss * W + col];
    for (int k = base; k < s; ++k) dc = dapply(A[(size_t)k * W + col], dc);
    int uc = CSU[ss * W + col];
    for (int k = base + SSL - 1; k > s; --k) uc = dapply(B[(size_t)k * W + col], uc);
    int r0 = s * L;
    for (int t = L - 1; t > i; --t)
        uc = down[(size_t)(r0 + t) * W + col] ? uc + 1 : 0;
    unsigned v = down[(size_t)(r0 + i) * W + col];
    uc = v ? uc + 1 : 0;
    int dv = (v < 128u) ? (int)v : (int)(v - 128u) + dc;
    int dd = min(min(dv, uc), DCLAMP);
    return (float)dd * (float)dd;
}

// ---------------------------------------------------------------------------
// K4: one block per (256-col tile, segment) = 2048 blocks (8/CU, 16 KB LDS).
// Prologue folds per-column carries from the superseg tables (uniform <=15
// A-loads + <=15 B-loads per column, coalesced, L2/L3-hot). Then decodes the
// f tile into LDS and runs the exact early-exit row scan; writes sqrt(D) and
// one atomicMax per block.
// ---------------------------------------------------------------------------
__global__ void __launch_bounds__(256)
k4_row(const unsigned char* __restrict__ down,
       const int* __restrict__ A, const int* __restrict__ B,
       const int* __restrict__ CSD, const int* __restrict__ CSU,
       float* __restrict__ dist, unsigned int* __restrict__ maxp) {
    __shared__ float ftile[L][LW];   // 16 KB
    __shared__ float smax[4];
    const int tid = threadIdx.x;
    const int s  = blockIdx.y;
    const int r0 = s * L;
    const int c0 = blockIdx.x * TILE;
    const int ss = s >> 4, base = ss << 4;

    {
        int lc = tid * 2;
        int gc = c0 - HALO + lc;       // even; gc+1 < W when gc >= 0
        if (gc >= 0 && gc < W) {
            int dc[2], uc[2];
#pragma unroll
            for (int k = 0; k < 2; ++k) {
                int col = gc + k;
                int c = CSD[ss * W + col];
                for (int t = base; t < s; ++t) c = dapply(A[(size_t)t * W + col], c);
                dc[k] = c;
                c = CSU[ss * W + col];
                for (int t = base + SSL - 1; t > s; --t) c = dapply(B[(size_t)t * W + col], c);
                uc[k] = c;
            }
            int u0 = uc[0], u1 = uc[1];
#pragma unroll
            for (int i = L - 1; i >= 0; --i) {
                unsigned v2 = *(const unsigned short*)(down + (size_t)(r0 + i) * W + gc);
                unsigned v0 = v2 & 0xffu, v1 = v2 >> 8;
                u0 = v0 ? u0 + 1 : 0;
                u1 = v1 ? u1 + 1 : 0;
                int dv0 = (v0 < 128u) ? (int)v0 : (int)(v0 - 128u) + dc[0];
                int dv1 = (v1 < 128u) ? (int)v1 : (int)(v1 - 128u) + dc[1];
                int dd0 = min(min(dv0, u0), DCLAMP);
                int dd1 = min(min(dv1, u1), DCLAMP);
                *(float2*)&ftile[i][lc] =
                    make_float2((float)dd0 * (float)dd0, (float)dd1 * (float)dd1);
            }
        } else {
#pragma unroll
            for (int i = 0; i < L; ++i)
                *(float2*)&ftile[i][lc] = make_float2(1e9f, 1e9f);  // pad: never wins
        }
    }
    __syncthreads();

    const int jj = c0 + tid;
    const int lj = HALO + tid;
    float res[L];
    float lmax = 0.0f;
    for (int i = 0; i < L; ++i) {
        float best = ftile[i][lj];
        for (int d = 1; d <= HALO && (float)(d * d) < best; ++d) {
            float q = (float)(d * d);
            best = fminf(best, ftile[i][lj - d] + q);
            best = fminf(best, ftile[i][lj + d] + q);
        }
        if ((float)((HALO + 1) * (HALO + 1)) < best) {
            for (int d = HALO + 1; d < W && (float)(d * d) < best; ++d) {
                float q = (float)(d * d);
                int jm = jj - d, jp = jj + d;
                if (jm >= 0) best = fminf(best, f_at(down, A, B, CSD, CSU, s, i, jm) + q);
                if (jp < W)  best = fminf(best, f_at(down, A, B, CSD, CSU, s, i, jp) + q);
            }
        }
        float r = sqrtf(best);
        res[i] = r;
        lmax = fmaxf(lmax, r);
    }
#pragma unroll
    for (int i = 0; i < L; ++i)
        dist[(size_t)(r0 + i) * W + jj] = res[i];

    for (int o = 32; o > 0; o >>= 1) lmax = fmaxf(lmax, __shfl_down(lmax, o, 64));
    if ((tid & 63) == 0) smax[tid >> 6] = lmax;
    __syncthreads();
    if (tid == 0)
        atomicMax(maxp, __float_as_uint(fmaxf(fmaxf(smax[0], smax[1]),
                                              fmaxf(smax[2], smax[3]))));
}

// ---------------------------------------------------------------------------
// K5: in-place normalize, float4 -> int4 (uint8 semantics: trunc(d/m*255)).
// ---------------------------------------------------------------------------
__global__ void k5_norm(int* __restrict__ out, const unsigned int* __restrict__ maxp) {
    size_t idx = ((size_t)blockIdx.x * blockDim.x + threadIdx.x) * 4;
    float m = __uint_as_float(*maxp);
    float4 dv = *(const float4*)((const float*)out + idx);
    float r[4] = {dv.x, dv.y, dv.z, dv.w};
    int o[4];
#pragma unroll
    for (int k = 0; k < 4; ++k) {
        float v = (m > 0.0f) ? (r[k] / m * 255.0f) : r[k];  // numpy op order
        v = fminf(fmaxf(v, 0.0f), 255.0f);
        o[k] = (int)v;                                      // trunc, like astype(uint8)
    }
    *(int4*)(out + idx) = make_int4(o[0], o[1], o[2], o[3]);
}

extern "C" void kernel_launch(void* const* d_in, const int* in_sizes, int n_in,
                              void* d_out, int out_size, void* d_ws, size_t ws_size,
                              hipStream_t stream) {
    const float* img = (const float*)d_in[0];
    int* out = (int*)d_out;

    // ws: down 4MB | A 2MB | B 2MB | SA | SB | CSD | CSU (128KB each) | maxp
    char* ws = (char*)d_ws;
    unsigned char* down = (unsigned char*)ws;
    int* A   = (int*)(ws + (size_t)H * W);
    int* B   = A + (size_t)SEG * W;
    int* SA  = B + (size_t)SEG * W;
    int* SB  = SA + (size_t)NSS * W;
    int* CSD = SB + (size_t)NSS * W;
    int* CSU = CSD + (size_t)NSS * W;
    unsigned int* maxp = (unsigned int*)(CSU + (size_t)NSS * W);

    dim3 blk(256);
    k1_down  <<<dim3(2, SEG), blk, 0, stream>>>(img, down, A, B, maxp);
    k2a_super<<<dim3(2 * NSS * W / 256), blk, 0, stream>>>(A, B, SA, SB);
    k2b_scan <<<dim3(2 * W / 256), blk, 0, stream>>>(SA, SB, CSD, CSU);
    k4_row   <<<dim3(W / TILE, SEG), blk, 0, stream>>>(down, A, B, CSD, CSU, (float*)out, maxp);
    k5_norm  <<<dim3(H * W / 1024), blk, 0, stream>>>(out, maxp);
}